// Round 12
// baseline (236.796 us; speedup 1.0000x reference)
//
#include <hip/hip_runtime.h>

// ---------------------------------------------------------------------------
// GCN encoder, N=50000, E=1.6M, D=128.
// Round 12 (= round 11 guard fix): padded-bucket CSR build (no coarse hist /
// global scan). Round 11 accidentally routed to the untested atomic fallback
// because the capacity guard used E*2 <= nb*CAP (false); correct check is
// mean bucket load + margin <= CAP.
// ---------------------------------------------------------------------------

#define D 128
#define BK_SHIFT 7            // 128 nodes per bucket
#define BK_NODES 128
#define NBMAX 512             // max buckets (N <= 65536)
#define CAP 7936              // slots per bucket (mean ~4092; ~60-sigma margin)
#define TILE_A 2048           // edges per block in k_bucketA

typedef __attribute__((ext_vector_type(8))) short bf16x8;
typedef __attribute__((ext_vector_type(4))) float f32x4;

static __device__ __forceinline__ unsigned f2bf(float f) {
  union { float f; unsigned u; } v; v.f = f;
  unsigned r = v.u + 0x7FFF + ((v.u >> 16) & 1);   // round to nearest even
  return r >> 16;
}
static __device__ __forceinline__ float bflo(unsigned u) {
  return __uint_as_float(u << 16);
}
static __device__ __forceinline__ float bfhi(unsigned u) {
  return __uint_as_float(u & 0xFFFF0000u);
}

// ---------------- CSR build (padded buckets) ----------------

// Single pass: LDS-batched per-bucket counts, direct global reservation,
// write packed (src | dstoff<<16 | bkt<<23) into bucket region bkt*CAP.
__global__ __launch_bounds__(256) void k_bucketA(const int* __restrict__ src,
                                                 const int* __restrict__ dst,
                                                 int* __restrict__ bcnt,
                                                 int* __restrict__ packed,
                                                 int E, int nb) {
  __shared__ int hist[NBMAX];
  __shared__ int base[NBMAX];
  __shared__ unsigned pv[TILE_A];
  int t = threadIdx.x;
  int e0 = blockIdx.x * TILE_A;

  for (int b = t; b < nb; b += 256) hist[b] = 0;
  __syncthreads();

  for (int i = t; i < TILE_A; i += 256) {
    int e = e0 + i;
    if (e < E) {
      int d = dst[e];
      int s = src[e];
      unsigned bkt = (unsigned)d >> BK_SHIFT;
      pv[i] = (unsigned)(s & 0xFFFF) | ((unsigned)(d & (BK_NODES - 1)) << 16) |
              (bkt << 23);
      atomicAdd(&hist[bkt], 1);
    }
  }
  __syncthreads();

  for (int b = t; b < nb; b += 256) {
    int h = hist[b];
    if (h) base[b] = atomicAdd(&bcnt[b], h);
  }
  __syncthreads();

  for (int i = t; i < TILE_A; i += 256) {
    int e = e0 + i;
    if (e < E) {
      unsigned v = pv[i];
      unsigned bkt = v >> 23;
      int pos = atomicAdd(&base[bkt], 1);
      if (pos < CAP) packed[(size_t)bkt * CAP + pos] = (int)(v & 0x7FFFFF);
    }
  }
}

// Per bucket: node-level LDS histogram -> rowBeg/rowEnd + dinv + sorted srcs
// (emitted as BYTE OFFSETS s<<8 into the 256B/row bf16 table), padded layout.
__global__ __launch_bounds__(512) void k_bucketB2(const int* __restrict__ packed,
                                                  const int* __restrict__ bcnt,
                                                  int* __restrict__ srcSorted,
                                                  int* __restrict__ rowBeg,
                                                  int* __restrict__ rowEnd,
                                                  float* __restrict__ dinv,
                                                  int n) {
  __shared__ int histC[BK_NODES];
  __shared__ int cur[BK_NODES];
  __shared__ int buf[CAP];
  int t = threadIdx.x;
  int bkt = blockIdx.x;
  int n0 = bkt << BK_SHIFT;
  int beg = bkt * CAP;
  int cnt = bcnt[bkt];
  if (cnt > CAP) cnt = CAP;

  if (t < BK_NODES) histC[t] = 0;
  __syncthreads();

  for (int i = t; i < cnt; i += 512)
    atomicAdd(&histC[packed[beg + i] >> 16], 1);
  __syncthreads();

  if (t == 0) {
    int run = 0;
#pragma unroll
    for (int j = 0; j < BK_NODES; ++j) { cur[j] = run; run += histC[j]; }
  }
  __syncthreads();

  if (t < BK_NODES && n0 + t < n) {
    int rb = beg + cur[t];
    rowBeg[n0 + t] = rb;
    rowEnd[n0 + t] = rb + histC[t];
    dinv[n0 + t]   = rsqrtf((float)histC[t] + 1.0f);
  }
  __syncthreads();   // rowBeg writes read cur before scatter mutates it

  for (int i = t; i < cnt; i += 512) {
    int p = packed[beg + i];
    int pos = atomicAdd(&cur[p >> 16], 1);
    buf[pos] = p & 0xFFFF;
  }
  __syncthreads();
  for (int i = t; i < cnt; i += 512)
    srcSorted[beg + i] = buf[i] << 8;             // byte offset
}

// ------------- aggregation (wave/node; pre-scaled bf16 table) ---------------
// T[s] = bf16(dinv[s]*h[s]) packed 2/word; srcSorted holds byte offsets s<<8.
// ox = dinv[d]*(T[d] + sum T[s]).
// EPI=1: h=relu((ox+bias)*mask); outB = bf16(dinv*h).  EPI=2: outB = bf16(ox).

template <int EPI>
__global__ __launch_bounds__(256) void k_aggb(const unsigned* __restrict__ T,
                                              const int* __restrict__ srcSorted,
                                              const int* __restrict__ rowBeg,
                                              const int* __restrict__ rowEnd,
                                              const float* __restrict__ dinv,
                                              const float* __restrict__ bias,
                                              const float* __restrict__ mask,
                                              unsigned* __restrict__ outB,
                                              int n) {
  int wave = (blockIdx.x * 256 + threadIdx.x) >> 6;
  int lane = threadIdx.x & 63;
  if (wave >= n) return;
  const char* Tb = (const char*)T;
  int lo = lane << 2;
  int beg = rowBeg[wave], end = rowEnd[wave];
  float a0x = 0.f, a0y = 0.f, a1x = 0.f, a1y = 0.f;
  float a2x = 0.f, a2y = 0.f, a3x = 0.f, a3y = 0.f;
  int j = beg;
  for (; j + 15 < end; j += 16) {
    unsigned u[16];
#pragma unroll
    for (int q = 0; q < 16; ++q) {
      int off = __builtin_nontemporal_load(srcSorted + j + q);
      u[q] = *(const unsigned*)(Tb + off + lo);
    }
#pragma unroll
    for (int q = 0; q < 16; q += 4) {
      a0x += bflo(u[q + 0]);  a0y += bfhi(u[q + 0]);
      a1x += bflo(u[q + 1]);  a1y += bfhi(u[q + 1]);
      a2x += bflo(u[q + 2]);  a2y += bfhi(u[q + 2]);
      a3x += bflo(u[q + 3]);  a3y += bfhi(u[q + 3]);
    }
  }
  for (; j + 7 < end; j += 8) {
    unsigned u[8];
#pragma unroll
    for (int q = 0; q < 8; ++q) {
      int off = __builtin_nontemporal_load(srcSorted + j + q);
      u[q] = *(const unsigned*)(Tb + off + lo);
    }
#pragma unroll
    for (int q = 0; q < 8; q += 4) {
      a0x += bflo(u[q + 0]);  a0y += bfhi(u[q + 0]);
      a1x += bflo(u[q + 1]);  a1y += bfhi(u[q + 1]);
      a2x += bflo(u[q + 2]);  a2y += bfhi(u[q + 2]);
      a3x += bflo(u[q + 3]);  a3y += bfhi(u[q + 3]);
    }
  }
  for (; j < end; ++j) {
    int off = __builtin_nontemporal_load(srcSorted + j);
    unsigned u = *(const unsigned*)(Tb + off + lo);
    a0x += bflo(u);
    a0y += bfhi(u);
  }
  unsigned us = T[(size_t)wave * 64 + lane];   // self term
  float dn = dinv[wave];
  float ox = ((a0x + a1x) + (a2x + a3x) + bflo(us)) * dn;
  float oy = ((a0y + a1y) + (a2y + a3y) + bfhi(us)) * dn;
  if (EPI == 1) {
    float2 bv = ((const float2*)bias)[lane];
    float2 mv = ((const float2*)mask)[(size_t)wave * 64 + lane];
    float hx = fmaxf((ox + bv.x) * mv.x, 0.f);
    float hy = fmaxf((oy + bv.y) * mv.y, 0.f);
    outB[(size_t)wave * 64 + lane] = f2bf(hx * dn) | (f2bf(hy * dn) << 16);
  } else {
    outB[(size_t)wave * 64 + lane] = f2bf(ox) | (f2bf(oy) << 16);
  }
}

// ------------- W -> bf16 preconvert (3 x 128x128) ---------------------------

__global__ __launch_bounds__(256) void k_wcvt(const float* __restrict__ W0,
                                              const float* __restrict__ W1,
                                              const float* __restrict__ W2,
                                              unsigned short* __restrict__ out) {
  int i = blockIdx.x * 256 + threadIdx.x;
  if (i >= 3 * 16384) return;
  const float* W = (i < 16384) ? W0 : (i < 32768 ? W1 : W2);
  out[i] = (unsigned short)f2bf(W[i & 16383]);
}

// ------------- MFMA GEMM: C = X @ W^T, 16x16x32 bf16, no LDS ---------------
// Wave computes 16 rows x 128 cols. A frag: row=lane&15, k=(lane>>4)*8+j.
// B frag: col=lane&15, same k over W[col][k]. C/D: col=lane&15,
// row=(lane>>4)*4+reg.

template <bool BF16IN, bool BF16OUT>
__global__ __launch_bounds__(256) void k_gemm_mfma(const void* __restrict__ Xv,
                                                   const unsigned short* __restrict__ Wb,
                                                   const float* __restrict__ bias,
                                                   const float* __restrict__ prescale,
                                                   float* __restrict__ Cf,
                                                   unsigned short* __restrict__ Cb,
                                                   int nrows) {
  int wid  = threadIdx.x >> 6;
  int lane = threadIdx.x & 63;
  int r0   = blockIdx.x * 64 + wid * 16;
  int arow = r0 + (lane & 15);
  int kb   = (lane >> 4) * 8;
  bool rowok = arow < nrows;

  bf16x8 a[4];
  if (BF16IN) {
    const unsigned short* X = (const unsigned short*)Xv;
#pragma unroll
    for (int ks = 0; ks < 4; ++ks) {
      bf16x8 t;
      if (rowok) t = *reinterpret_cast<const bf16x8*>(X + (size_t)arow * D + ks * 32 + kb);
      else { for (int q = 0; q < 8; ++q) t[q] = 0; }
      a[ks] = t;
    }
  } else {
    const float* X = (const float*)Xv;
#pragma unroll
    for (int ks = 0; ks < 4; ++ks) {
      bf16x8 t;
      if (rowok) {
        const float* p = X + (size_t)arow * D + ks * 32 + kb;
        float4 f0 = *(const float4*)(p);
        float4 f1 = *(const float4*)(p + 4);
        t[0] = (short)f2bf(f0.x); t[1] = (short)f2bf(f0.y);
        t[2] = (short)f2bf(f0.z); t[3] = (short)f2bf(f0.w);
        t[4] = (short)f2bf(f1.x); t[5] = (short)f2bf(f1.y);
        t[6] = (short)f2bf(f1.z); t[7] = (short)f2bf(f1.w);
      } else {
        for (int q = 0; q < 8; ++q) t[q] = 0;
      }
      a[ks] = t;
    }
  }

  int rbase = r0 + (lane >> 4) * 4;
  float sc[4];
  if (BF16OUT) {
#pragma unroll
    for (int reg = 0; reg < 4; ++reg) {
      int rr = rbase + reg;
      sc[reg] = (prescale && rr < nrows) ? prescale[rr] : 1.0f;
    }
  }

#pragma unroll
  for (int ct = 0; ct < 8; ++ct) {
    int col = ct * 16 + (lane & 15);
    f32x4 acc = {0.f, 0.f, 0.f, 0.f};
#pragma unroll
    for (int ks = 0; ks < 4; ++ks) {
      bf16x8 b = *reinterpret_cast<const bf16x8*>(Wb + (size_t)col * D + ks * 32 + kb);
      acc = __builtin_amdgcn_mfma_f32_16x16x32_bf16(a[ks], b, acc, 0, 0, 0);
    }
    if (BF16OUT) {
#pragma unroll
      for (int reg = 0; reg < 4; ++reg) {
        int rr = rbase + reg;
        if (rr < nrows)
          Cb[(size_t)rr * D + col] = (unsigned short)f2bf(acc[reg] * sc[reg]);
      }
    } else {
      float bc = bias ? bias[col] : 0.f;
#pragma unroll
      for (int reg = 0; reg < 4; ++reg) {
        int rr = rbase + reg;
        if (rr < nrows) Cf[(size_t)rr * D + col] = acc[reg] + bc;
      }
    }
  }
}

// Fused dual GEMM: C1 = X@W1^T + b1, C2 = X@W2^T + b2 (bf16 in, f32 out).
__global__ __launch_bounds__(256) void k_gemm_mfma2(const unsigned short* __restrict__ X,
                                                    const unsigned short* __restrict__ W1b,
                                                    const unsigned short* __restrict__ W2b,
                                                    const float* __restrict__ b1,
                                                    const float* __restrict__ b2,
                                                    float* __restrict__ C1,
                                                    float* __restrict__ C2,
                                                    int nrows) {
  int wid  = threadIdx.x >> 6;
  int lane = threadIdx.x & 63;
  int r0   = blockIdx.x * 64 + wid * 16;
  int arow = r0 + (lane & 15);
  int kb   = (lane >> 4) * 8;
  bool rowok = arow < nrows;

  bf16x8 a[4];
#pragma unroll
  for (int ks = 0; ks < 4; ++ks) {
    bf16x8 t;
    if (rowok) t = *reinterpret_cast<const bf16x8*>(X + (size_t)arow * D + ks * 32 + kb);
    else { for (int q = 0; q < 8; ++q) t[q] = 0; }
    a[ks] = t;
  }

  int rbase = r0 + (lane >> 4) * 4;

#pragma unroll
  for (int wm = 0; wm < 2; ++wm) {
    const unsigned short* Wb = (wm == 0) ? W1b : W2b;
    const float* bias        = (wm == 0) ? b1 : b2;
    float* Cf                = (wm == 0) ? C1 : C2;
#pragma unroll
    for (int ct = 0; ct < 8; ++ct) {
      int col = ct * 16 + (lane & 15);
      f32x4 acc = {0.f, 0.f, 0.f, 0.f};
#pragma unroll
      for (int ks = 0; ks < 4; ++ks) {
        bf16x8 b = *reinterpret_cast<const bf16x8*>(Wb + (size_t)col * D + ks * 32 + kb);
        acc = __builtin_amdgcn_mfma_f32_16x16x32_bf16(a[ks], b, acc, 0, 0, 0);
      }
      float bc = bias[col];
#pragma unroll
      for (int reg = 0; reg < 4; ++reg) {
        int rr = rbase + reg;
        if (rr < nrows) Cf[(size_t)rr * D + col] = acc[reg] + bc;
      }
    }
  }
}

// ---------------- fallback path (atomic, all f32) ----------------

__global__ __launch_bounds__(256) void k_deg_f(const int* __restrict__ dst,
                                               float* __restrict__ deg, int E) {
  int i = blockIdx.x * 256 + threadIdx.x;
  if (i < E) atomicAdd(&deg[dst[i]], 1.0f);
}

__global__ __launch_bounds__(256) void k_dinv_f(float* __restrict__ deg, int n) {
  int i = blockIdx.x * 256 + threadIdx.x;
  if (i < n) deg[i] = rsqrtf(deg[i] + 1.0f);
}

__global__ __launch_bounds__(256) void k_selfmul(const float* __restrict__ X,
                                                 const float* __restrict__ dinv,
                                                 float* __restrict__ out, int n) {
  int i = blockIdx.x * 256 + threadIdx.x;
  if (i >= n * 32) return;
  int r = i >> 5, c4 = (i & 31) << 2;
  float di = dinv[r];
  float s = di * di;
  float4 h = *(const float4*)(X + (size_t)r * D + c4);
  h.x *= s; h.y *= s; h.z *= s; h.w *= s;
  *(float4*)(out + (size_t)r * D + c4) = h;
}

__global__ __launch_bounds__(256) void k_relumask(float* __restrict__ h,
                                                  const float* __restrict__ mask, int n) {
  int i = blockIdx.x * 256 + threadIdx.x;
  if (i >= n * 32) return;
  float4 v = *(const float4*)(h + (size_t)i * 4);
  float4 m = *(const float4*)(mask + (size_t)i * 4);
  v.x = fmaxf(v.x * m.x, 0.f);
  v.y = fmaxf(v.y * m.y, 0.f);
  v.z = fmaxf(v.z * m.z, 0.f);
  v.w = fmaxf(v.w * m.w, 0.f);
  *(float4*)(h + (size_t)i * 4) = v;
}

__global__ __launch_bounds__(256) void k_aggatomic(const float* __restrict__ X,
                                                   const int* __restrict__ src,
                                                   const int* __restrict__ dst,
                                                   const float* __restrict__ dinv,
                                                   float* __restrict__ out, int E) {
  int gid = blockIdx.x * 256 + threadIdx.x;
  int wave = gid >> 6;
  int lane = threadIdx.x & 63;
  int nw = (gridDim.x * 256) >> 6;
  for (int e = wave; e < E; e += nw) {
    int s = src[e], d = dst[e];
    float nrm = dinv[s] * dinv[d];
    float2 v = ((const float2*)(X + (size_t)s * D))[lane];
    float* op = out + (size_t)d * D + lane * 2;
    atomicAdd(op, v.x * nrm);
    atomicAdd(op + 1, v.y * nrm);
  }
}

__global__ __launch_bounds__(256) void k_addbias(float* __restrict__ C,
                                                 const float* __restrict__ bias, int n) {
  int i = blockIdx.x * 256 + threadIdx.x;
  if (i >= n * 32) return;
  int c4 = (i & 31) << 2;
  float4 v = *(const float4*)(C + (size_t)i * 4);
  float4 b = *(const float4*)(bias + c4);
  v.x += b.x; v.y += b.y; v.z += b.z; v.w += b.w;
  *(float4*)(C + (size_t)i * 4) = v;
}

template <bool BF16OUT>
__global__ __launch_bounds__(256) void k_gemm128(const float* __restrict__ X,
                                                 const float* __restrict__ W,
                                                 const float* __restrict__ bias,
                                                 const float* __restrict__ prescale,
                                                 float* __restrict__ Cf,
                                                 unsigned short* __restrict__ Cb,
                                                 int nrows) {
  __shared__ float Xs[64][132];
  __shared__ float Ws[32][128];

  int tid = threadIdx.x;
  int row0 = blockIdx.x * 64;

  for (int t = tid; t < 2048; t += 256) {
    int r = t >> 5;
    int c4 = (t & 31) << 2;
    int gr = row0 + r;
    float4 v = make_float4(0.f, 0.f, 0.f, 0.f);
    if (gr < nrows) v = *(const float4*)(X + (size_t)gr * D + c4);
    Xs[r][c4 + 0] = v.x; Xs[r][c4 + 1] = v.y;
    Xs[r][c4 + 2] = v.z; Xs[r][c4 + 3] = v.w;
  }

  float acc[4][8];
#pragma unroll
  for (int i = 0; i < 4; ++i)
#pragma unroll
    for (int j = 0; j < 8; ++j) acc[i][j] = 0.f;

  int ty = tid >> 4, tx = tid & 15;
  int r0 = ty << 2, c0 = tx << 3;

  for (int k0 = 0; k0 < 128; k0 += 32) {
    int j = tid >> 1;
    int kkb = (tid & 1) << 4;
    const float4* wp = (const float4*)(W + j * D + k0 + kkb);
    float4 wa = wp[0], wb = wp[1], wc = wp[2], wd = wp[3];

    __syncthreads();
    Ws[kkb +  0][j] = wa.x; Ws[kkb +  1][j] = wa.y; Ws[kkb +  2][j] = wa.z; Ws[kkb +  3][j] = wa.w;
    Ws[kkb +  4][j] = wb.x; Ws[kkb +  5][j] = wb.y; Ws[kkb +  6][j] = wb.z; Ws[kkb +  7][j] = wb.w;
    Ws[kkb +  8][j] = wc.x; Ws[kkb +  9][j] = wc.y; Ws[kkb + 10][j] = wc.z; Ws[kkb + 11][j] = wc.w;
    Ws[kkb + 12][j] = wd.x; Ws[kkb + 13][j] = wd.y; Ws[kkb + 14][j] = wd.z; Ws[kkb + 15][j] = wd.w;
    __syncthreads();

#pragma unroll
    for (int kk = 0; kk < 32; ++kk) {
      float xi[4];
      xi[0] = Xs[r0 + 0][k0 + kk];
      xi[1] = Xs[r0 + 1][k0 + kk];
      xi[2] = Xs[r0 + 2][k0 + kk];
      xi[3] = Xs[r0 + 3][k0 + kk];
      float4 wv0 = *(const float4*)(&Ws[kk][c0]);
      float4 wv1 = *(const float4*)(&Ws[kk][c0 + 4]);
      float wf[8] = {wv0.x, wv0.y, wv0.z, wv0.w, wv1.x, wv1.y, wv1.z, wv1.w};
#pragma unroll
      for (int i = 0; i < 4; ++i)
#pragma unroll
        for (int jj = 0; jj < 8; ++jj) acc[i][jj] += xi[i] * wf[jj];
    }
  }

  float4 bv0 = make_float4(0.f, 0.f, 0.f, 0.f);
  float4 bv1 = make_float4(0.f, 0.f, 0.f, 0.f);
  if (bias) {
    bv0 = *(const float4*)(bias + c0);
    bv1 = *(const float4*)(bias + c0 + 4);
  }

#pragma unroll
  for (int i = 0; i < 4; ++i) {
    int gr = row0 + r0 + i;
    if (gr < nrows) {
      float o[8];
      o[0] = acc[i][0] + bv0.x; o[1] = acc[i][1] + bv0.y;
      o[2] = acc[i][2] + bv0.z; o[3] = acc[i][3] + bv0.w;
      o[4] = acc[i][4] + bv1.x; o[5] = acc[i][5] + bv1.y;
      o[6] = acc[i][6] + bv1.z; o[7] = acc[i][7] + bv1.w;
      if (BF16OUT) {
        float dn = prescale ? prescale[gr] : 1.0f;
        uint4 pk;
        pk.x = f2bf(o[0] * dn) | (f2bf(o[1] * dn) << 16);
        pk.y = f2bf(o[2] * dn) | (f2bf(o[3] * dn) << 16);
        pk.z = f2bf(o[4] * dn) | (f2bf(o[5] * dn) << 16);
        pk.w = f2bf(o[6] * dn) | (f2bf(o[7] * dn) << 16);
        *(uint4*)(Cb + (size_t)gr * D + c0) = pk;
      } else {
        *(float4*)(Cf + (size_t)gr * D + c0)     = make_float4(o[0], o[1], o[2], o[3]);
        *(float4*)(Cf + (size_t)gr * D + c0 + 4) = make_float4(o[4], o[5], o[6], o[7]);
      }
    }
  }
}

// ---------------- launch ----------------

extern "C" void kernel_launch(void* const* d_in, const int* in_sizes, int n_in,
                              void* d_out, int out_size, void* d_ws, size_t ws_size,
                              hipStream_t stream) {
  const float* x    = (const float*)d_in[0];
  const int*   ei   = (const int*)d_in[1];
  const float* mask = (const float*)d_in[2];
  const float* W0   = (const float*)d_in[3];
  const float* b0   = (const float*)d_in[4];
  const float* W1   = (const float*)d_in[5];
  const float* b1   = (const float*)d_in[6];
  const float* W2   = (const float*)d_in[7];
  const float* b2   = (const float*)d_in[8];

  const int N = in_sizes[0] / D;
  const int E = in_sizes[1] / 2;
  const int* srcv = ei;
  const int* dstv = ei + E;

  float* out  = (float*)d_out;
  float* outA = out;                    // x_
  float* outB = out + (size_t)N * D;    // x2

  const size_t featBytes  = (size_t)N * D * sizeof(float);
  const size_t featBytesH = (size_t)N * D * sizeof(short);
  const int gGemm  = (N + 63) / 64;
  const int gEdge  = (E + 255) / 256;
  const int gNode  = (N + 255) / 256;
  const int gWaveN = (N + 3) / 4;
  const int gElem  = (N * 32 + 255) / 256;
  const int nb     = (N + BK_NODES - 1) >> BK_SHIFT;
  const int gBA    = (E + TILE_A - 1) / TILE_A;
  const size_t padBytes = (size_t)nb * CAP * 4;

  auto align256 = [](size_t v) { return (v + 255) & ~(size_t)255; };
  char* w = (char*)d_ws;
  size_t off = 0;
  int*   bcnt      = (int*)(w + off);   off = align256(off + NBMAX * 4);
  int*   rowBeg    = (int*)(w + off);   off = align256(off + (size_t)N * 4);
  int*   rowEnd    = (int*)(w + off);   off = align256(off + (size_t)N * 4);
  float* dinv      = (float*)(w + off); off = align256(off + (size_t)N * 4);
  int*   srcSorted = (int*)(w + off);   off = align256(off + padBytes);
  unsigned short* Wb = (unsigned short*)(w + off); off = align256(off + 3 * 16384 * 2);
  unsigned* h0bf   = (unsigned*)(w + off); off = align256(off + featBytesH);
  unsigned* hbf    = (unsigned*)(w + off); off = align256(off + featBytesH);
  unsigned* gbf    = (unsigned*)(w + off); off = align256(off + featBytesH);
  int*   packed    = (int*)gbf;         // aliases gbf (consumed before written)
  size_t need = off;

  // Guard: mean bucket load + ~16-sigma margin must fit CAP (round-11 bug:
  // used E*2 <= nb*CAP which is FALSE here and routed to the fallback).
  if (ws_size >= need && N <= 65536 && nb <= NBMAX &&
      padBytes <= featBytesH && (E / nb) + 1024 <= CAP) {
    // ---- CSR build (2 kernels + tiny memset) ----
    hipMemsetAsync(bcnt, 0, (size_t)nb * sizeof(int), stream);
    k_bucketA<<<gBA, 256, 0, stream>>>(srcv, dstv, bcnt, packed, E, nb);
    k_bucketB2<<<nb, 512, 0, stream>>>(packed, bcnt, srcSorted, rowBeg,
                                       rowEnd, dinv, N);
    // weights -> bf16 (W0 | W1 | W2 at Wb, Wb+16384, Wb+32768)
    k_wcvt<<<192, 256, 0, stream>>>(W0, W1, W2, Wb);

    // t0 = bf16(dinv * (x @ W0^T))
    k_gemm_mfma<false, true><<<gGemm, 256, 0, stream>>>(
        x, Wb, nullptr, dinv, nullptr, (unsigned short*)h0bf, N);
    // t1 = bf16(dinv * relu((agg + b0) * mask))
    k_aggb<1><<<gWaveN, 256, 0, stream>>>(h0bf, srcSorted, rowBeg, rowEnd,
                                          dinv, b0, mask, hbf, N);
    // g = bf16(agg)
    k_aggb<2><<<gWaveN, 256, 0, stream>>>(hbf, srcSorted, rowBeg, rowEnd,
                                          dinv, nullptr, nullptr, gbf, N);
    // x_ = g @ W1^T + b1 ; x2 = g @ W2^T + b2 (fused)
    k_gemm_mfma2<<<gGemm, 256, 0, stream>>>(
        (const unsigned short*)gbf, Wb + 16384, Wb + 32768, b1, b2,
        outA, outB, N);
  } else {
    // ---- atomic fallback (commuted, 2 aggs, all f32) ----
    float* fdinv = (float*)(w);
    float* fA    = (float*)(w + 0x40000);
    float* fB    = (float*)((char*)fA + featBytes);
    hipMemsetAsync(fdinv, 0, (size_t)N * sizeof(float), stream);
    k_deg_f<<<gEdge, 256, 0, stream>>>(dstv, fdinv, E);
    k_dinv_f<<<gNode, 256, 0, stream>>>(fdinv, N);
    k_gemm128<false><<<gGemm, 256, 0, stream>>>(x, W0, nullptr, nullptr, fB, nullptr, N);
    k_selfmul<<<gElem, 256, 0, stream>>>(fB, fdinv, fA, N);
    k_aggatomic<<<4096, 256, 0, stream>>>(fB, srcv, dstv, fdinv, fA, E);
    k_addbias<<<gElem, 256, 0, stream>>>(fA, b0, N);
    k_relumask<<<gElem, 256, 0, stream>>>(fA, mask, N);
    k_selfmul<<<gElem, 256, 0, stream>>>(fA, fdinv, fB, N);
    k_aggatomic<<<4096, 256, 0, stream>>>(fA, srcv, dstv, fdinv, fB, E);
    k_gemm128<false><<<gGemm, 256, 0, stream>>>(fB, W1, b1, nullptr, outA, nullptr, N);
    k_gemm128<false><<<gGemm, 256, 0, stream>>>(fB, W2, b2, nullptr, outB, nullptr, N);
  }
}

// Round 13
// 223.504 us; speedup vs baseline: 1.0595x; 1.0595x over previous
//
#include <hip/hip_runtime.h>

// ---------------------------------------------------------------------------
// GCN encoder, N=50000, E=1.6M, D=128.
// Round 13: fix round-12 agg regression. (a) srcSorted compact again via
// global-cursor reservation in bucketB2 (no scan, no padded footprint);
// (b) revert nontemporal index loads (regular cached); (c) fold W->bf16
// conversion into bucketA (one fewer dispatch).
// ---------------------------------------------------------------------------

#define D 128
#define BK_SHIFT 7            // 128 nodes per bucket
#define BK_NODES 128
#define NBMAX 512             // max buckets (N <= 65536)
#define CAP 7936              // slots per bucket (mean ~4092; ~60-sigma margin)
#define TILE_A 2048           // edges per block in k_bucketA

typedef __attribute__((ext_vector_type(8))) short bf16x8;
typedef __attribute__((ext_vector_type(4))) float f32x4;

static __device__ __forceinline__ unsigned f2bf(float f) {
  union { float f; unsigned u; } v; v.f = f;
  unsigned r = v.u + 0x7FFF + ((v.u >> 16) & 1);   // round to nearest even
  return r >> 16;
}
static __device__ __forceinline__ float bflo(unsigned u) {
  return __uint_as_float(u << 16);
}
static __device__ __forceinline__ float bfhi(unsigned u) {
  return __uint_as_float(u & 0xFFFF0000u);
}

// ---------------- CSR build (padded packed regions, compact srcSorted) ------

// Single pass: LDS-batched per-bucket counts, direct global reservation,
// write packed (src | dstoff<<16 | bkt<<23) into bucket region bkt*CAP.
// First 192 blocks also convert W0|W1|W2 (f32) -> Wb (bf16), 256 elems each.
__global__ __launch_bounds__(256) void k_bucketA(const int* __restrict__ src,
                                                 const int* __restrict__ dst,
                                                 int* __restrict__ bcnt,
                                                 int* __restrict__ packed,
                                                 const float* __restrict__ W0,
                                                 const float* __restrict__ W1,
                                                 const float* __restrict__ W2,
                                                 unsigned short* __restrict__ Wb,
                                                 int E, int nb) {
  __shared__ int hist[NBMAX];
  __shared__ int base[NBMAX];
  __shared__ unsigned pv[TILE_A];
  int t = threadIdx.x;
  int e0 = blockIdx.x * TILE_A;

  // piggyback: W -> bf16 (3*16384 elems over first 192 blocks)
  if (blockIdx.x < 192) {
    int i = blockIdx.x * 256 + t;
    const float* W = (i < 16384) ? W0 : (i < 32768 ? W1 : W2);
    Wb[i] = (unsigned short)f2bf(W[i & 16383]);
  }

  for (int b = t; b < nb; b += 256) hist[b] = 0;
  __syncthreads();

  for (int i = t; i < TILE_A; i += 256) {
    int e = e0 + i;
    if (e < E) {
      int d = dst[e];
      int s = src[e];
      unsigned bkt = (unsigned)d >> BK_SHIFT;
      pv[i] = (unsigned)(s & 0xFFFF) | ((unsigned)(d & (BK_NODES - 1)) << 16) |
              (bkt << 23);
      atomicAdd(&hist[bkt], 1);
    }
  }
  __syncthreads();

  for (int b = t; b < nb; b += 256) {
    int h = hist[b];
    if (h) base[b] = atomicAdd(&bcnt[b], h);
  }
  __syncthreads();

  for (int i = t; i < TILE_A; i += 256) {
    int e = e0 + i;
    if (e < E) {
      unsigned v = pv[i];
      unsigned bkt = v >> 23;
      int pos = atomicAdd(&base[bkt], 1);
      if (pos < CAP) packed[(size_t)bkt * CAP + pos] = (int)(v & 0x7FFFFF);
    }
  }
}

// Per bucket: node-level LDS histogram -> rowBeg/rowEnd + dinv + sorted srcs
// (BYTE OFFSETS s<<8). srcSorted written COMPACTLY at a region reserved from
// a global cursor (bucket order in srcSorted is irrelevant: rowBeg/rowEnd
// are explicit per-node pointers).
__global__ __launch_bounds__(512) void k_bucketB2(const int* __restrict__ packed,
                                                  const int* __restrict__ bcnt,
                                                  int* __restrict__ gcur,
                                                  int* __restrict__ srcSorted,
                                                  int* __restrict__ rowBeg,
                                                  int* __restrict__ rowEnd,
                                                  float* __restrict__ dinv,
                                                  int n) {
  __shared__ int histC[BK_NODES];
  __shared__ int cur[BK_NODES];
  __shared__ int buf[CAP];
  __shared__ int obase;
  int t = threadIdx.x;
  int bkt = blockIdx.x;
  int n0 = bkt << BK_SHIFT;
  int beg = bkt * CAP;
  int cnt = bcnt[bkt];
  if (cnt > CAP) cnt = CAP;

  if (t < BK_NODES) histC[t] = 0;
  __syncthreads();

  for (int i = t; i < cnt; i += 512)
    atomicAdd(&histC[packed[beg + i] >> 16], 1);
  __syncthreads();

  if (t == 0) {
    int run = 0;
#pragma unroll
    for (int j = 0; j < BK_NODES; ++j) { cur[j] = run; run += histC[j]; }
    obase = atomicAdd(gcur, run);   // compact reservation
  }
  __syncthreads();

  if (t < BK_NODES && n0 + t < n) {
    int rb = obase + cur[t];
    rowBeg[n0 + t] = rb;
    rowEnd[n0 + t] = rb + histC[t];
    dinv[n0 + t]   = rsqrtf((float)histC[t] + 1.0f);
  }
  __syncthreads();   // rowBeg writes read cur before scatter mutates it

  for (int i = t; i < cnt; i += 512) {
    int p = packed[beg + i];
    int pos = atomicAdd(&cur[p >> 16], 1);
    buf[pos] = p & 0xFFFF;
  }
  __syncthreads();
  for (int i = t; i < cnt; i += 512)
    srcSorted[obase + i] = buf[i] << 8;           // byte offset, compact
}

// ------------- aggregation (wave/node; pre-scaled bf16 table) ---------------
// T[s] = bf16(dinv[s]*h[s]) packed 2/word; srcSorted holds byte offsets s<<8.
// ox = dinv[d]*(T[d] + sum T[s]).
// EPI=1: h=relu((ox+bias)*mask); outB = bf16(dinv*h).  EPI=2: outB = bf16(ox).

template <int EPI>
__global__ __launch_bounds__(256) void k_aggb(const unsigned* __restrict__ T,
                                              const int* __restrict__ srcSorted,
                                              const int* __restrict__ rowBeg,
                                              const int* __restrict__ rowEnd,
                                              const float* __restrict__ dinv,
                                              const float* __restrict__ bias,
                                              const float* __restrict__ mask,
                                              unsigned* __restrict__ outB,
                                              int n) {
  int wave = (blockIdx.x * 256 + threadIdx.x) >> 6;
  int lane = threadIdx.x & 63;
  if (wave >= n) return;
  const char* Tb = (const char*)T;
  int lo = lane << 2;
  int beg = rowBeg[wave], end = rowEnd[wave];
  float a0x = 0.f, a0y = 0.f, a1x = 0.f, a1y = 0.f;
  float a2x = 0.f, a2y = 0.f, a3x = 0.f, a3y = 0.f;
  int j = beg;
  for (; j + 15 < end; j += 16) {
    unsigned u[16];
#pragma unroll
    for (int q = 0; q < 16; ++q)
      u[q] = *(const unsigned*)(Tb + srcSorted[j + q] + lo);
#pragma unroll
    for (int q = 0; q < 16; q += 4) {
      a0x += bflo(u[q + 0]);  a0y += bfhi(u[q + 0]);
      a1x += bflo(u[q + 1]);  a1y += bfhi(u[q + 1]);
      a2x += bflo(u[q + 2]);  a2y += bfhi(u[q + 2]);
      a3x += bflo(u[q + 3]);  a3y += bfhi(u[q + 3]);
    }
  }
  for (; j + 7 < end; j += 8) {
    unsigned u[8];
#pragma unroll
    for (int q = 0; q < 8; ++q)
      u[q] = *(const unsigned*)(Tb + srcSorted[j + q] + lo);
#pragma unroll
    for (int q = 0; q < 8; q += 4) {
      a0x += bflo(u[q + 0]);  a0y += bfhi(u[q + 0]);
      a1x += bflo(u[q + 1]);  a1y += bfhi(u[q + 1]);
      a2x += bflo(u[q + 2]);  a2y += bfhi(u[q + 2]);
      a3x += bflo(u[q + 3]);  a3y += bfhi(u[q + 3]);
    }
  }
  for (; j < end; ++j) {
    unsigned u = *(const unsigned*)(Tb + srcSorted[j] + lo);
    a0x += bflo(u);
    a0y += bfhi(u);
  }
  unsigned us = T[(size_t)wave * 64 + lane];   // self term
  float dn = dinv[wave];
  float ox = ((a0x + a1x) + (a2x + a3x) + bflo(us)) * dn;
  float oy = ((a0y + a1y) + (a2y + a3y) + bfhi(us)) * dn;
  if (EPI == 1) {
    float2 bv = ((const float2*)bias)[lane];
    float2 mv = ((const float2*)mask)[(size_t)wave * 64 + lane];
    float hx = fmaxf((ox + bv.x) * mv.x, 0.f);
    float hy = fmaxf((oy + bv.y) * mv.y, 0.f);
    outB[(size_t)wave * 64 + lane] = f2bf(hx * dn) | (f2bf(hy * dn) << 16);
  } else {
    outB[(size_t)wave * 64 + lane] = f2bf(ox) | (f2bf(oy) << 16);
  }
}

// ------------- MFMA GEMM: C = X @ W^T, 16x16x32 bf16, no LDS ---------------
// Wave computes 16 rows x 128 cols. A frag: row=lane&15, k=(lane>>4)*8+j.
// B frag: col=lane&15, same k over W[col][k]. C/D: col=lane&15,
// row=(lane>>4)*4+reg.

template <bool BF16IN, bool BF16OUT>
__global__ __launch_bounds__(256) void k_gemm_mfma(const void* __restrict__ Xv,
                                                   const unsigned short* __restrict__ Wb,
                                                   const float* __restrict__ bias,
                                                   const float* __restrict__ prescale,
                                                   float* __restrict__ Cf,
                                                   unsigned short* __restrict__ Cb,
                                                   int nrows) {
  int wid  = threadIdx.x >> 6;
  int lane = threadIdx.x & 63;
  int r0   = blockIdx.x * 64 + wid * 16;
  int arow = r0 + (lane & 15);
  int kb   = (lane >> 4) * 8;
  bool rowok = arow < nrows;

  bf16x8 a[4];
  if (BF16IN) {
    const unsigned short* X = (const unsigned short*)Xv;
#pragma unroll
    for (int ks = 0; ks < 4; ++ks) {
      bf16x8 t;
      if (rowok) t = *reinterpret_cast<const bf16x8*>(X + (size_t)arow * D + ks * 32 + kb);
      else { for (int q = 0; q < 8; ++q) t[q] = 0; }
      a[ks] = t;
    }
  } else {
    const float* X = (const float*)Xv;
#pragma unroll
    for (int ks = 0; ks < 4; ++ks) {
      bf16x8 t;
      if (rowok) {
        const float* p = X + (size_t)arow * D + ks * 32 + kb;
        float4 f0 = *(const float4*)(p);
        float4 f1 = *(const float4*)(p + 4);
        t[0] = (short)f2bf(f0.x); t[1] = (short)f2bf(f0.y);
        t[2] = (short)f2bf(f0.z); t[3] = (short)f2bf(f0.w);
        t[4] = (short)f2bf(f1.x); t[5] = (short)f2bf(f1.y);
        t[6] = (short)f2bf(f1.z); t[7] = (short)f2bf(f1.w);
      } else {
        for (int q = 0; q < 8; ++q) t[q] = 0;
      }
      a[ks] = t;
    }
  }

  int rbase = r0 + (lane >> 4) * 4;
  float sc[4];
  if (BF16OUT) {
#pragma unroll
    for (int reg = 0; reg < 4; ++reg) {
      int rr = rbase + reg;
      sc[reg] = (prescale && rr < nrows) ? prescale[rr] : 1.0f;
    }
  }

#pragma unroll
  for (int ct = 0; ct < 8; ++ct) {
    int col = ct * 16 + (lane & 15);
    f32x4 acc = {0.f, 0.f, 0.f, 0.f};
#pragma unroll
    for (int ks = 0; ks < 4; ++ks) {
      bf16x8 b = *reinterpret_cast<const bf16x8*>(Wb + (size_t)col * D + ks * 32 + kb);
      acc = __builtin_amdgcn_mfma_f32_16x16x32_bf16(a[ks], b, acc, 0, 0, 0);
    }
    if (BF16OUT) {
#pragma unroll
      for (int reg = 0; reg < 4; ++reg) {
        int rr = rbase + reg;
        if (rr < nrows)
          Cb[(size_t)rr * D + col] = (unsigned short)f2bf(acc[reg] * sc[reg]);
      }
    } else {
      float bc = bias ? bias[col] : 0.f;
#pragma unroll
      for (int reg = 0; reg < 4; ++reg) {
        int rr = rbase + reg;
        if (rr < nrows) Cf[(size_t)rr * D + col] = acc[reg] + bc;
      }
    }
  }
}

// Fused dual GEMM: C1 = X@W1^T + b1, C2 = X@W2^T + b2 (bf16 in, f32 out).
__global__ __launch_bounds__(256) void k_gemm_mfma2(const unsigned short* __restrict__ X,
                                                    const unsigned short* __restrict__ W1b,
                                                    const unsigned short* __restrict__ W2b,
                                                    const float* __restrict__ b1,
                                                    const float* __restrict__ b2,
                                                    float* __restrict__ C1,
                                                    float* __restrict__ C2,
                                                    int nrows) {
  int wid  = threadIdx.x >> 6;
  int lane = threadIdx.x & 63;
  int r0   = blockIdx.x * 64 + wid * 16;
  int arow = r0 + (lane & 15);
  int kb   = (lane >> 4) * 8;
  bool rowok = arow < nrows;

  bf16x8 a[4];
#pragma unroll
  for (int ks = 0; ks < 4; ++ks) {
    bf16x8 t;
    if (rowok) t = *reinterpret_cast<const bf16x8*>(X + (size_t)arow * D + ks * 32 + kb);
    else { for (int q = 0; q < 8; ++q) t[q] = 0; }
    a[ks] = t;
  }

  int rbase = r0 + (lane >> 4) * 4;

#pragma unroll
  for (int wm = 0; wm < 2; ++wm) {
    const unsigned short* Wb = (wm == 0) ? W1b : W2b;
    const float* bias        = (wm == 0) ? b1 : b2;
    float* Cf                = (wm == 0) ? C1 : C2;
#pragma unroll
    for (int ct = 0; ct < 8; ++ct) {
      int col = ct * 16 + (lane & 15);
      f32x4 acc = {0.f, 0.f, 0.f, 0.f};
#pragma unroll
      for (int ks = 0; ks < 4; ++ks) {
        bf16x8 b = *reinterpret_cast<const bf16x8*>(Wb + (size_t)col * D + ks * 32 + kb);
        acc = __builtin_amdgcn_mfma_f32_16x16x32_bf16(a[ks], b, acc, 0, 0, 0);
      }
      float bc = bias[col];
#pragma unroll
      for (int reg = 0; reg < 4; ++reg) {
        int rr = rbase + reg;
        if (rr < nrows) Cf[(size_t)rr * D + col] = acc[reg] + bc;
      }
    }
  }
}

// ---------------- fallback path (atomic, all f32) ----------------

__global__ __launch_bounds__(256) void k_deg_f(const int* __restrict__ dst,
                                               float* __restrict__ deg, int E) {
  int i = blockIdx.x * 256 + threadIdx.x;
  if (i < E) atomicAdd(&deg[dst[i]], 1.0f);
}

__global__ __launch_bounds__(256) void k_dinv_f(float* __restrict__ deg, int n) {
  int i = blockIdx.x * 256 + threadIdx.x;
  if (i < n) deg[i] = rsqrtf(deg[i] + 1.0f);
}

__global__ __launch_bounds__(256) void k_selfmul(const float* __restrict__ X,
                                                 const float* __restrict__ dinv,
                                                 float* __restrict__ out, int n) {
  int i = blockIdx.x * 256 + threadIdx.x;
  if (i >= n * 32) return;
  int r = i >> 5, c4 = (i & 31) << 2;
  float di = dinv[r];
  float s = di * di;
  float4 h = *(const float4*)(X + (size_t)r * D + c4);
  h.x *= s; h.y *= s; h.z *= s; h.w *= s;
  *(float4*)(out + (size_t)r * D + c4) = h;
}

__global__ __launch_bounds__(256) void k_relumask(float* __restrict__ h,
                                                  const float* __restrict__ mask, int n) {
  int i = blockIdx.x * 256 + threadIdx.x;
  if (i >= n * 32) return;
  float4 v = *(const float4*)(h + (size_t)i * 4);
  float4 m = *(const float4*)(mask + (size_t)i * 4);
  v.x = fmaxf(v.x * m.x, 0.f);
  v.y = fmaxf(v.y * m.y, 0.f);
  v.z = fmaxf(v.z * m.z, 0.f);
  v.w = fmaxf(v.w * m.w, 0.f);
  *(float4*)(h + (size_t)i * 4) = v;
}

__global__ __launch_bounds__(256) void k_aggatomic(const float* __restrict__ X,
                                                   const int* __restrict__ src,
                                                   const int* __restrict__ dst,
                                                   const float* __restrict__ dinv,
                                                   float* __restrict__ out, int E) {
  int gid = blockIdx.x * 256 + threadIdx.x;
  int wave = gid >> 6;
  int lane = threadIdx.x & 63;
  int nw = (gridDim.x * 256) >> 6;
  for (int e = wave; e < E; e += nw) {
    int s = src[e], d = dst[e];
    float nrm = dinv[s] * dinv[d];
    float2 v = ((const float2*)(X + (size_t)s * D))[lane];
    float* op = out + (size_t)d * D + lane * 2;
    atomicAdd(op, v.x * nrm);
    atomicAdd(op + 1, v.y * nrm);
  }
}

__global__ __launch_bounds__(256) void k_addbias(float* __restrict__ C,
                                                 const float* __restrict__ bias, int n) {
  int i = blockIdx.x * 256 + threadIdx.x;
  if (i >= n * 32) return;
  int c4 = (i & 31) << 2;
  float4 v = *(const float4*)(C + (size_t)i * 4);
  float4 b = *(const float4*)(bias + c4);
  v.x += b.x; v.y += b.y; v.z += b.z; v.w += b.w;
  *(float4*)(C + (size_t)i * 4) = v;
}

template <bool BF16OUT>
__global__ __launch_bounds__(256) void k_gemm128(const float* __restrict__ X,
                                                 const float* __restrict__ W,
                                                 const float* __restrict__ bias,
                                                 const float* __restrict__ prescale,
                                                 float* __restrict__ Cf,
                                                 unsigned short* __restrict__ Cb,
                                                 int nrows) {
  __shared__ float Xs[64][132];
  __shared__ float Ws[32][128];

  int tid = threadIdx.x;
  int row0 = blockIdx.x * 64;

  for (int t = tid; t < 2048; t += 256) {
    int r = t >> 5;
    int c4 = (t & 31) << 2;
    int gr = row0 + r;
    float4 v = make_float4(0.f, 0.f, 0.f, 0.f);
    if (gr < nrows) v = *(const float4*)(X + (size_t)gr * D + c4);
    Xs[r][c4 + 0] = v.x; Xs[r][c4 + 1] = v.y;
    Xs[r][c4 + 2] = v.z; Xs[r][c4 + 3] = v.w;
  }

  float acc[4][8];
#pragma unroll
  for (int i = 0; i < 4; ++i)
#pragma unroll
    for (int j = 0; j < 8; ++j) acc[i][j] = 0.f;

  int ty = tid >> 4, tx = tid & 15;
  int r0 = ty << 2, c0 = tx << 3;

  for (int k0 = 0; k0 < 128; k0 += 32) {
    int j = tid >> 1;
    int kkb = (tid & 1) << 4;
    const float4* wp = (const float4*)(W + j * D + k0 + kkb);
    float4 wa = wp[0], wb = wp[1], wc = wp[2], wd = wp[3];

    __syncthreads();
    Ws[kkb +  0][j] = wa.x; Ws[kkb +  1][j] = wa.y; Ws[kkb +  2][j] = wa.z; Ws[kkb +  3][j] = wa.w;
    Ws[kkb +  4][j] = wb.x; Ws[kkb +  5][j] = wb.y; Ws[kkb +  6][j] = wb.z; Ws[kkb +  7][j] = wb.w;
    Ws[kkb +  8][j] = wc.x; Ws[kkb +  9][j] = wc.y; Ws[kkb + 10][j] = wc.z; Ws[kkb + 11][j] = wc.w;
    Ws[kkb + 12][j] = wd.x; Ws[kkb + 13][j] = wd.y; Ws[kkb + 14][j] = wd.z; Ws[kkb + 15][j] = wd.w;
    __syncthreads();

#pragma unroll
    for (int kk = 0; kk < 32; ++kk) {
      float xi[4];
      xi[0] = Xs[r0 + 0][k0 + kk];
      xi[1] = Xs[r0 + 1][k0 + kk];
      xi[2] = Xs[r0 + 2][k0 + kk];
      xi[3] = Xs[r0 + 3][k0 + kk];
      float4 wv0 = *(const float4*)(&Ws[kk][c0]);
      float4 wv1 = *(const float4*)(&Ws[kk][c0 + 4]);
      float wf[8] = {wv0.x, wv0.y, wv0.z, wv0.w, wv1.x, wv1.y, wv1.z, wv1.w};
#pragma unroll
      for (int i = 0; i < 4; ++i)
#pragma unroll
        for (int jj = 0; jj < 8; ++jj) acc[i][jj] += xi[i] * wf[jj];
    }
  }

  float4 bv0 = make_float4(0.f, 0.f, 0.f, 0.f);
  float4 bv1 = make_float4(0.f, 0.f, 0.f, 0.f);
  if (bias) {
    bv0 = *(const float4*)(bias + c0);
    bv1 = *(const float4*)(bias + c0 + 4);
  }

#pragma unroll
  for (int i = 0; i < 4; ++i) {
    int gr = row0 + r0 + i;
    if (gr < nrows) {
      float o[8];
      o[0] = acc[i][0] + bv0.x; o[1] = acc[i][1] + bv0.y;
      o[2] = acc[i][2] + bv0.z; o[3] = acc[i][3] + bv0.w;
      o[4] = acc[i][4] + bv1.x; o[5] = acc[i][5] + bv1.y;
      o[6] = acc[i][6] + bv1.z; o[7] = acc[i][7] + bv1.w;
      if (BF16OUT) {
        float dn = prescale ? prescale[gr] : 1.0f;
        uint4 pk;
        pk.x = f2bf(o[0] * dn) | (f2bf(o[1] * dn) << 16);
        pk.y = f2bf(o[2] * dn) | (f2bf(o[3] * dn) << 16);
        pk.z = f2bf(o[4] * dn) | (f2bf(o[5] * dn) << 16);
        pk.w = f2bf(o[6] * dn) | (f2bf(o[7] * dn) << 16);
        *(uint4*)(Cb + (size_t)gr * D + c0) = pk;
      } else {
        *(float4*)(Cf + (size_t)gr * D + c0)     = make_float4(o[0], o[1], o[2], o[3]);
        *(float4*)(Cf + (size_t)gr * D + c0 + 4) = make_float4(o[4], o[5], o[6], o[7]);
      }
    }
  }
}

// ---------------- launch ----------------

extern "C" void kernel_launch(void* const* d_in, const int* in_sizes, int n_in,
                              void* d_out, int out_size, void* d_ws, size_t ws_size,
                              hipStream_t stream) {
  const float* x    = (const float*)d_in[0];
  const int*   ei   = (const int*)d_in[1];
  const float* mask = (const float*)d_in[2];
  const float* W0   = (const float*)d_in[3];
  const float* b0   = (const float*)d_in[4];
  const float* W1   = (const float*)d_in[5];
  const float* b1   = (const float*)d_in[6];
  const float* W2   = (const float*)d_in[7];
  const float* b2   = (const float*)d_in[8];

  const int N = in_sizes[0] / D;
  const int E = in_sizes[1] / 2;
  const int* srcv = ei;
  const int* dstv = ei + E;

  float* out  = (float*)d_out;
  float* outA = out;                    // x_
  float* outB = out + (size_t)N * D;    // x2

  const size_t featBytes  = (size_t)N * D * sizeof(float);
  const size_t featBytesH = (size_t)N * D * sizeof(short);
  const int gGemm  = (N + 63) / 64;
  const int gEdge  = (E + 255) / 256;
  const int gNode  = (N + 255) / 256;
  const int gWaveN = (N + 3) / 4;
  const int gElem  = (N * 32 + 255) / 256;
  const int nb     = (N + BK_NODES - 1) >> BK_SHIFT;
  const int gBA    = (E + TILE_A - 1) / TILE_A;
  const size_t padBytes = (size_t)nb * CAP * 4;   // packed (aliases gbf)

  auto align256 = [](size_t v) { return (v + 255) & ~(size_t)255; };
  char* w = (char*)d_ws;
  size_t off = 0;
  int*   bcnt      = (int*)(w + off);   off = align256(off + (NBMAX + 1) * 4);
  int*   gcur      = bcnt + NBMAX;      // one extra int, zeroed with bcnt
  int*   rowBeg    = (int*)(w + off);   off = align256(off + (size_t)N * 4);
  int*   rowEnd    = (int*)(w + off);   off = align256(off + (size_t)N * 4);
  float* dinv      = (float*)(w + off); off = align256(off + (size_t)N * 4);
  int*   srcSorted = (int*)(w + off);   off = align256(off + (size_t)E * 4);
  unsigned short* Wb = (unsigned short*)(w + off); off = align256(off + 3 * 16384 * 2);
  unsigned* h0bf   = (unsigned*)(w + off); off = align256(off + featBytesH);
  unsigned* hbf    = (unsigned*)(w + off); off = align256(off + featBytesH);
  size_t gbfOff    = off;
  unsigned* gbf    = (unsigned*)(w + off);
  size_t offA = off + featBytesH;                       // end if gbf >= packed
  size_t offB = off + padBytes;                         // end if packed > gbf
  off = align256(offA > offB ? offA : offB);
  int*   packed    = (int*)gbf;         // aliases gbf (consumed before written)
  size_t need = off;
  (void)gbfOff;

  // Guard: mean bucket load + ~16-sigma margin must fit CAP.
  if (ws_size >= need && N <= 65536 && nb <= NBMAX &&
      (E / nb) + 1024 <= CAP) {
    // ---- CSR build (2 kernels + tiny memset); bucketA also converts W ----
    hipMemsetAsync(bcnt, 0, (size_t)(NBMAX + 1) * sizeof(int), stream);
    k_bucketA<<<gBA, 256, 0, stream>>>(srcv, dstv, bcnt, packed,
                                       W0, W1, W2, Wb, E, nb);
    k_bucketB2<<<nb, 512, 0, stream>>>(packed, bcnt, gcur, srcSorted,
                                       rowBeg, rowEnd, dinv, N);

    // t0 = bf16(dinv * (x @ W0^T))
    k_gemm_mfma<false, true><<<gGemm, 256, 0, stream>>>(
        x, Wb, nullptr, dinv, nullptr, (unsigned short*)h0bf, N);
    // t1 = bf16(dinv * relu((agg + b0) * mask))
    k_aggb<1><<<gWaveN, 256, 0, stream>>>(h0bf, srcSorted, rowBeg, rowEnd,
                                          dinv, b0, mask, hbf, N);
    // g = bf16(agg)
    k_aggb<2><<<gWaveN, 256, 0, stream>>>(hbf, srcSorted, rowBeg, rowEnd,
                                          dinv, nullptr, nullptr, gbf, N);
    // x_ = g @ W1^T + b1 ; x2 = g @ W2^T + b2 (fused)
    k_gemm_mfma2<<<gGemm, 256, 0, stream>>>(
        (const unsigned short*)gbf, Wb + 16384, Wb + 32768, b1, b2,
        outA, outB, N);
  } else {
    // ---- atomic fallback (commuted, 2 aggs, all f32) ----
    float* fdinv = (float*)(w);
    float* fA    = (float*)(w + 0x40000);
    float* fB    = (float*)((char*)fA + featBytes);
    hipMemsetAsync(fdinv, 0, (size_t)N * sizeof(float), stream);
    k_deg_f<<<gEdge, 256, 0, stream>>>(dstv, fdinv, E);
    k_dinv_f<<<gNode, 256, 0, stream>>>(fdinv, N);
    k_gemm128<false><<<gGemm, 256, 0, stream>>>(x, W0, nullptr, nullptr, fB, nullptr, N);
    k_selfmul<<<gElem, 256, 0, stream>>>(fB, fdinv, fA, N);
    k_aggatomic<<<4096, 256, 0, stream>>>(fB, srcv, dstv, fdinv, fA, E);
    k_addbias<<<gElem, 256, 0, stream>>>(fA, b0, N);
    k_relumask<<<gElem, 256, 0, stream>>>(fA, mask, N);
    k_selfmul<<<gElem, 256, 0, stream>>>(fA, fdinv, fB, N);
    k_aggatomic<<<4096, 256, 0, stream>>>(fA, srcv, dstv, fdinv, fB, E);
    k_gemm128<false><<<gGemm, 256, 0, stream>>>(fB, W1, b1, nullptr, outA, nullptr, N);
    k_gemm128<false><<<gGemm, 256, 0, stream>>>(fB, W2, b2, nullptr, outB, nullptr, N);
  }
}